// Round 11
// baseline (201.321 us; speedup 1.0000x reference)
//
#include <hip/hip_runtime.h>
#include <hip/hip_bf16.h>
#include <math.h>
#include <stdint.h>
#include <string.h>

#define TSEQ 2048
#define DMODEL 1024
#define NH 16
#define HD 64
#define BROWS 4096   // b*t
#define BH 32        // b*h

typedef __attribute__((ext_vector_type(8))) short short8;
typedef __attribute__((ext_vector_type(4))) float floatx4;

#define MFMA16 __builtin_amdgcn_mfma_f32_16x16x32_bf16
// 3-bit chunk-XOR swizzle on 64-short (128 B) rows
#define SWZ8(r, q) ((((q) ^ ((r) & 7)) * 8))

#define QSCALE 0.18033688011112042f   // 0.125 * log2(e); p = exp2(s) = exp(s/log2e)

__device__ __forceinline__ unsigned short bf16_rne(float f) {
    uint32_t u = __float_as_uint(f);
    u += 0x7FFFu + ((u >> 16) & 1u);
    return (unsigned short)(u >> 16);
}

__device__ __forceinline__ uint32_t pack_bf16x2(float a, float b) {
    __hip_bfloat162 h = __float22bfloat162_rn(float2{a, b});
    uint32_t r;
    memcpy(&r, &h, 4);
    return r;
}

__device__ __forceinline__ void split_bf16(float f, short& hi, short& lo) {
    uint32_t u = __float_as_uint(f);
    hi = (short)(u >> 16);
    float hif = __uint_as_float(u & 0xFFFF0000u);
    lo = (short)bf16_rne(f - hif);
}

__device__ __forceinline__ void async16(const void* g, void* l) {
    __builtin_amdgcn_global_load_lds(
        (__attribute__((address_space(1))) const uint32_t*)g,
        (__attribute__((address_space(3))) uint32_t*)l, 16, 0, 0);
}

// ---------------------------------------------------------------------------
// Fused pack (unchanged)
// ---------------------------------------------------------------------------
struct PackArgs {
    const float4* x;
    ushort4* xb;
    const float4* w[3];   // Wq, Wk, Wv
    ushort4* wb[3];
    const float4* wo;
    ushort4* woh;
    ushort4* wol;
};
__global__ __launch_bounds__(256) void pack_all(PackArgs a) {
    const int y = blockIdx.y;
    const int base = blockIdx.x * 256 + threadIdx.x;
    if (y == 0) {
#pragma unroll
        for (int it = 0; it < 4; ++it) {
            int i = base + it * 262144;
            float4 f = a.x[i];
            a.xb[i] = make_ushort4(bf16_rne(f.x), bf16_rne(f.y),
                                   bf16_rne(f.z), bf16_rne(f.w));
        }
    } else if (y <= 3) {
        int w = y - 1;
        float4 f = a.w[w][base];
        a.wb[w][base] = make_ushort4(bf16_rne(f.x), bf16_rne(f.y),
                                     bf16_rne(f.z), bf16_rne(f.w));
    } else {
        float4 f = a.wo[base];
        short h0, l0, h1, l1, h2, l2, h3, l3;
        split_bf16(f.x, h0, l0); split_bf16(f.y, h1, l1);
        split_bf16(f.z, h2, l2); split_bf16(f.w, h3, l3);
        a.woh[base] = make_ushort4(h0, h1, h2, h3);
        a.wol[base] = make_ushort4(l0, l1, l2, l3);
    }
}

// ---------------------------------------------------------------------------
// Fused QKV GEMM (R7-form): 128x128, BK=64, 4 waves 64x64/wave,
// dbuf 64 KB, counted vmcnt(8), XCD swizzle. Unchanged.
// ---------------------------------------------------------------------------
#define QSTAGE(DB, K0)                                                          \
    {                                                                           \
        _Pragma("unroll")                                                       \
        for (int j = 0; j < 8; ++j) {                                           \
            int idx = wave * 8 + j;                                             \
            int sub = idx & 15;                                                 \
            const short* s = (idx < 16) ? Asrc : Bsrc;                          \
            short* d = (idx < 16) ? sA[DB] : sB[DB];                            \
            async16(s + (size_t)(sub * 8 + srow) * K + (K0) + soff, d + sub * 512); \
        }                                                                       \
    }

__global__ __launch_bounds__(256) void gemm_qkv(
    const short* __restrict__ Xb,
    const short* __restrict__ Bq, const short* __restrict__ Bk,
    const short* __restrict__ Bv,
    short* __restrict__ Qo, short* __restrict__ Ko, short* __restrict__ Vo) {
    __shared__ short sA[2][128 * 64];
    __shared__ short sB[2][128 * 64];
    const int K = DMODEL;

    const int tid = threadIdx.x;
    const int lane = tid & 63, wave = tid >> 6;
    const int quad = lane >> 4, col = lane & 15;

    // XCD swizzle: lin = by*24+bx; xcd owns bx' = 3*xcd + (j%3), all by'
    const int lin = blockIdx.y * 24 + blockIdx.x;
    const int xcd = lin & 7, j8 = lin >> 3;          // j8 in [0,96)
    const int bxp = 3 * xcd + (j8 % 3);
    const int byp = j8 / 3;
    const int m0 = byp * 128, n0 = bxp * 128;
    const int which = n0 >> 10;
    const int nn0 = n0 & 1023;
    const int wm = wave >> 1, wn = wave & 1;

    const short* B = (which == 0) ? Bq : (which == 1) ? Bk : Bv;
    const short* Asrc = Xb + (size_t)m0 * K;
    const short* Bsrc = B + (size_t)nn0 * K;

    const int srow = lane >> 3;
    const int soff = (((lane & 7) ^ srow) * 8);

    floatx4 acc[4][4] = {};

    QSTAGE(0, 0);
    for (int t = 0; t < 16; ++t) {
        const int db = t & 1;
        if (t < 15) {
            QSTAGE(db ^ 1, (t + 1) * 64);
            asm volatile("s_waitcnt vmcnt(8)" ::: "memory");
        } else {
            asm volatile("s_waitcnt vmcnt(0)" ::: "memory");
        }
        __builtin_amdgcn_s_barrier();

#pragma unroll
        for (int s2 = 0; s2 < 2; ++s2) {
            short8 a_b[4], b_b[4];
#pragma unroll
            for (int mi = 0; mi < 4; ++mi) {
                int r = wm * 64 + mi * 16 + col;
                a_b[mi] = *(const short8*)&sA[db][r * 64 + SWZ8(r, s2 * 4 + quad)];
            }
#pragma unroll
            for (int ni = 0; ni < 4; ++ni) {
                int r = wn * 64 + ni * 16 + col;
                b_b[ni] = *(const short8*)&sB[db][r * 64 + SWZ8(r, s2 * 4 + quad)];
            }
            __builtin_amdgcn_s_setprio(1);
            if (which == 2) {
#pragma unroll
                for (int mi = 0; mi < 4; ++mi)
#pragma unroll
                    for (int ni = 0; ni < 4; ++ni)
                        acc[mi][ni] = MFMA16(a_b[mi], b_b[ni], acc[mi][ni], 0, 0, 0);
            } else {
#pragma unroll
                for (int mi = 0; mi < 4; ++mi)
#pragma unroll
                    for (int ni = 0; ni < 4; ++ni)
                        acc[mi][ni] = MFMA16(b_b[ni], a_b[mi], acc[mi][ni], 0, 0, 0);
            }
            __builtin_amdgcn_s_setprio(0);
        }
        __builtin_amdgcn_s_barrier();
    }

    const int mb = m0 + wm * 64;
    const int nlb = nn0 + wn * 64;
    if (which == 2) {
        // V^T [bh][hd][t], kappa-permuted window position + chunk-XOR swizzle
#pragma unroll
        for (int ni = 0; ni < 4; ++ni) {
            int n = nlb + ni * 16 + col;
            int h = n >> 6, hd = n & 63;
#pragma unroll
            for (int mi = 0; mi < 4; ++mi) {
                int m4 = mb + mi * 16 + quad * 4;
                int b = m4 >> 11, t0 = m4 & 2047;
                // kappa^-1: key bits [t5][t4][t3t2][t1t0] -> s = [t5][t3t2][t4][t1t0]
                int sw = (t0 & 32) | ((t0 & 12) << 1) | ((t0 & 16) >> 2);
                int tsw = (t0 & ~63) | ((((sw >> 3) ^ (hd & 7)) << 3) | (sw & 7));
                size_t row = ((size_t)(b * NH + h) * HD + hd) * TSEQ;
                *(ushort4*)&Vo[row + tsw] =
                    make_ushort4(bf16_rne(acc[mi][ni][0]), bf16_rne(acc[mi][ni][1]),
                                 bf16_rne(acc[mi][ni][2]), bf16_rne(acc[mi][ni][3]));
            }
        }
    } else {
        short* O = (which == 0) ? Qo : Ko;
        const float sc = (which == 0) ? QSCALE : 1.0f;
#pragma unroll
        for (int mi = 0; mi < 4; ++mi) {
            int m = mb + mi * 16 + col;
            int b = m >> 11, t = m & 2047;
#pragma unroll
            for (int ni = 0; ni < 4; ++ni) {
                int n = nlb + ni * 16 + quad * 4;
                int h = n >> 6, hd = n & 63;
                int hds = (which == 1) ? ((((hd >> 3) ^ (t & 7)) << 3) | (hd & 7)) : hd;
                size_t idx = ((size_t)(b * NH + h) * TSEQ + t) * HD + hds;
                *(ushort4*)&O[idx] =
                    make_ushort4(bf16_rne(acc[mi][ni][0] * sc), bf16_rne(acc[mi][ni][1] * sc),
                                 bf16_rne(acc[mi][ni][2] * sc), bf16_rne(acc[mi][ni][3] * sc));
            }
        }
    }
}

// ---------------------------------------------------------------------------
// Flash attention, R11: K fragments read DIRECTLY from global (L2-resident
// via XCD swizzle: 4 bh/XCD = 1 MB K in 4 MB L2; K's packed layout is
// row-contiguous so each fragment instruction touches 16 full 64-B sectors).
// V stays LDS-staged (TSEQ-strided layout is uncoalesced for direct reads).
// sK eliminated: LDS 64->32 KB, LDS reads/tile/wave 32->16, ONE barrier +
// one trivial vmcnt(0) per 64-key tile (V-stage is a full tile old).
// K global address arithmetic == old LDS image offsets (layout identical).
// T15 interleave retained.
// ---------------------------------------------------------------------------
typedef union { short8 v; uint32_t w[4]; } pfu;

// pf word c from s: 8 exp2 + 4 cvt_pk
#define EXPPACK_C(S, C, PFW)                                                    \
    {                                                                           \
        float p0 = __builtin_amdgcn_exp2f(S[2 * (C)][0]);                       \
        float p1 = __builtin_amdgcn_exp2f(S[2 * (C)][1]);                       \
        float p2 = __builtin_amdgcn_exp2f(S[2 * (C)][2]);                       \
        float p3 = __builtin_amdgcn_exp2f(S[2 * (C)][3]);                       \
        float p4 = __builtin_amdgcn_exp2f(S[2 * (C) + 1][0]);                   \
        float p5 = __builtin_amdgcn_exp2f(S[2 * (C) + 1][1]);                   \
        float p6 = __builtin_amdgcn_exp2f(S[2 * (C) + 1][2]);                   \
        float p7 = __builtin_amdgcn_exp2f(S[2 * (C) + 1][3]);                   \
        PFW.w[0] = pack_bf16x2(p0, p1);                                         \
        PFW.w[1] = pack_bf16x2(p2, p3);                                         \
        PFW.w[2] = pack_bf16x2(p4, p5);                                         \
        PFW.w[3] = pack_bf16x2(p6, p7);                                         \
    }

#define PV_C(DB, U, C, PFW)                                                     \
    {                                                                           \
        const short* vbc = (C) ? vb1 : vb0;                                     \
        __builtin_amdgcn_s_setprio(1);                                          \
        lacc = MFMA16(ones.v, PFW.v, lacc, 0, 0, 0);                            \
        _Pragma("unroll")                                                       \
        for (int ni = 0; ni < 4; ++ni) {                                        \
            short8 vf = *(const short8*)(vbc + (DB) * 8192 + (U) * 4096 + ni * 1024); \
            O[ni] = MFMA16(vf, PFW.v, O[ni], 0, 0, 0);                          \
        }                                                                       \
        __builtin_amdgcn_s_setprio(0);                                          \
    }

// 8 K-fragment global loads for subtile U (addresses = old LDS image offsets)
#define KLOAD_U(U, KF)                                                          \
    {                                                                           \
        _Pragma("unroll")                                                       \
        for (int k4 = 0; k4 < 4; ++k4) {                                        \
            KF[2 * k4]     = *(const short8*)(gk0 + (U) * 4096 + k4 * 1024);    \
            KF[2 * k4 + 1] = *(const short8*)(gk1 + (U) * 4096 + k4 * 1024);    \
        }                                                                       \
    }

#define QK_FROM(KF, S)                                                          \
    {                                                                           \
        __builtin_amdgcn_s_setprio(1);                                          \
        _Pragma("unroll")                                                       \
        for (int k4 = 0; k4 < 4; ++k4) {                                        \
            S[k4] = MFMA16(KF[2 * k4], qf[0], S[k4], 0, 0, 0);                  \
            S[k4] = MFMA16(KF[2 * k4 + 1], qf[1], S[k4], 0, 0, 0);              \
        }                                                                       \
        __builtin_amdgcn_s_setprio(0);                                          \
    }

#define ATTN_COMPUTE_G(DB)                                                      \
    {                                                                           \
        short8 ka[8];                                                           \
        KLOAD_U(0, ka);                                                         \
        floatx4 sa[4] = {};                                                     \
        QK_FROM(ka, sa);                                                        \
        short8 kb_[8];                                                          \
        KLOAD_U(1, kb_);          /* u1 loads in flight during u0 VALU */       \
        pfu pfA0, pfA1;                                                         \
        EXPPACK_C(sa, 0, pfA0);                                                 \
        EXPPACK_C(sa, 1, pfA1);                                                 \
        floatx4 sb[4] = {};                                                     \
        QK_FROM(kb_, sb);                                                       \
        pfu pfB0, pfB1;                                                         \
        PV_C(DB, 0, 0, pfA0);                                                   \
        EXPPACK_C(sb, 0, pfB0);                                                 \
        PV_C(DB, 0, 1, pfA1);                                                   \
        EXPPACK_C(sb, 1, pfB1);                                                 \
        PV_C(DB, 1, 0, pfB0);                                                   \
        PV_C(DB, 1, 1, pfB1);                                                   \
    }

// V staging: 2 slots/wave (16 x 1KB covers the 16 KB 128-key V-tile)
#define VSTAGE(D0, D1)                                                          \
    {                                                                           \
        async16(gv0, D0);                                                       \
        async16(gv1, D1);                                                       \
        gv0 += 128; gv1 += 128;                                                 \
    }

__global__ __launch_bounds__(512, 4) void attn_bf16(
    const short* __restrict__ Qb, const short* __restrict__ Kb,
    const short* __restrict__ Vb, short* __restrict__ Cb) {
    __shared__ short sV[2][2][4096];   // [dbuf][tile64] — 32 KB

    const int tid = threadIdx.x;
    const int lane = tid & 63, wave = tid >> 6;
    const int quad = lane >> 4, col = lane & 15;

    // XCD swizzle: XCD xcd owns bh in {4*xcd..4*xcd+3} -> K/V L2-resident
    const int lin = blockIdx.y * 16 + blockIdx.x;
    const int xcd = lin & 7, j8 = lin >> 3;          // j8 in [0,64)
    const int qt = j8 & 15;
    const int bh = 4 * xcd + (j8 >> 4);
    const size_t bhoff = (size_t)bh * TSEQ * HD;

    // Q as B-operand frags: B[n=q=col][k=quad*8+j]
    const size_t qrow = (size_t)(qt * 128 + wave * 16 + col) * HD;
    short8 qf[2];
#pragma unroll
    for (int c = 0; c < 2; ++c)
        qf[c] = *(const short8*)&Qb[bhoff + qrow + c * 32 + quad * 8];

    const int srow = lane >> 3;
    const int schunk = (lane & 7) * 8;   // V globally pre-swizzled

    // V staging: slots n = wave*2 + {0,1}; tile = n>>3, sub = n&7
    const int n0_ = wave * 2, n1_ = n0_ + 1;
    const int tl0 = n0_ >> 3, sb0 = n0_ & 7;
    const int tl1 = n1_ >> 3, sb1 = n1_ & 7;
    const short* gv0 = Vb + bhoff + (size_t)(sb0 * 8 + srow) * TSEQ + tl0 * 64 + schunk;
    const short* gv1 = Vb + bhoff + (size_t)(sb1 * 8 + srow) * TSEQ + tl1 * 64 + schunk;
    short* vd0_0 = &sV[0][tl0][sb0 * 512];
    short* vd0_1 = &sV[0][tl1][sb1 * 512];
    short* vd1_0 = &sV[1][tl0][sb0 * 512];
    short* vd1_1 = &sV[1][tl1][sb1 * 512];

    // K direct-read bases (global). Offsets identical to old LDS image:
    // kf(U,k4,c) at gk_c + U*4096 + k4*1024 shorts; advance 8192/tile.
    const int ch0 = ((quad ^ (col & 7)) << 3);
    const int ch1 = (((4 + quad) ^ (col & 7)) << 3);
    const short* gk0 = Kb + bhoff + col * HD + ch0;
    const short* gk1 = Kb + bhoff + col * HD + ch1;

    // V LDS fragment-read bases
    const short* vb0 = &sV[0][0][col * 64 + ch0];
    const short* vb1 = &sV[0][0][col * 64 + ch1];

    // bf16 1.0 x8 for the l-accumulating MFMA
    union { short8 v; short s[8]; } ones;
#pragma unroll
    for (int j = 0; j < 8; ++j) ones.s[j] = (short)0x3F80;

    floatx4 lacc = {};      // every element = running l for q = col
    floatx4 O[4] = {};      // O^T: hd = ni*16 + quad*4 + r, q = col

    // prologue: V(0) -> db0
    VSTAGE(vd0_0, vd0_1);
    asm volatile("s_waitcnt vmcnt(0)" ::: "memory");
    __builtin_amdgcn_s_barrier();

    for (int kt2 = 0; kt2 < 8; ++kt2) {
        // tile 2*kt2 (db0): stage V(t+1) -> db1, compute, wait+barrier
        VSTAGE(vd1_0, vd1_1);
        ATTN_COMPUTE_G(0);
        gk0 += 8192; gk1 += 8192;
        asm volatile("s_waitcnt vmcnt(0)" ::: "memory");
        __builtin_amdgcn_s_barrier();

        // tile 2*kt2+1 (db1): stage V(t+1) -> db0 (skip on last tile)
        if (kt2 < 7) {
            VSTAGE(vd0_0, vd0_1);
        }
        ATTN_COMPUTE_G(1);
        gk0 += 8192; gk1 += 8192;
        asm volatile("s_waitcnt vmcnt(0)" ::: "memory");
        __builtin_amdgcn_s_barrier();
    }

    // l is fully summed over all keys by the ones-MFMA (B-layout spans k=0..31)
    const float inv = 1.0f / lacc[0];

    const int b = bh >> 4, h = bh & 15;
    const int trow = qt * 128 + wave * 16 + col;
    const size_t obase = (size_t)(b * TSEQ + trow) * DMODEL + h * 64;
#pragma unroll
    for (int ni = 0; ni < 4; ++ni) {
        uint2 pk;
        pk.x = pack_bf16x2(O[ni][0] * inv, O[ni][1] * inv);
        pk.y = pack_bf16x2(O[ni][2] * inv, O[ni][3] * inv);
        *(uint2*)&Cb[obase + ni * 16 + quad * 4] = pk;
    }
}

// ---------------------------------------------------------------------------
// Out-proj 2-term (R7 form: dbuf + vmcnt(8) + XCD swizzle). Unchanged.
// ---------------------------------------------------------------------------
#define OSTAGE(DB, K0)                                                          \
    {                                                                           \
        _Pragma("unroll")                                                       \
        for (int j = 0; j < 8; ++j) {                                           \
            int idx = wave * 8 + j;                                             \
            int buf = (idx < 16) ? 0 : (idx < 24) ? 1 : 2;                      \
            int sub = (buf == 0) ? idx : (buf == 1) ? idx - 16 : idx - 24;      \
            const short* s = (buf == 0) ? Asrc : (buf == 1) ? Bhsrc : Blsrc;    \
            short* d = (buf == 0) ? sA[DB] : (buf == 1) ? sBh[DB] : sBl[DB];    \
            async16(s + (size_t)(sub * 8 + srow) * K + (K0) + soff, d + sub * 512); \
        }                                                                       \
    }

__global__ __launch_bounds__(256) void gemm_out(
    const short* __restrict__ Ab,
    const short* __restrict__ Bh, const short* __restrict__ Bl,
    const float* __restrict__ bias, float* __restrict__ Of) {
    __shared__ short sA[2][128 * 64];
    __shared__ short sBh[2][64 * 64];
    __shared__ short sBl[2][64 * 64];
    const int K = DMODEL, N = DMODEL;

    const int tid = threadIdx.x;
    const int lane = tid & 63, wave = tid >> 6;
    const int quad = lane >> 4, col = lane & 15;

    // XCD swizzle: lin = by*16+bx; xcd owns bx' = 2*xcd + (j&1), all by'
    const int lin = blockIdx.y * 16 + blockIdx.x;
    const int xcd = lin & 7, j8 = lin >> 3;          // j8 in [0,64)
    const int bxp = 2 * xcd + (j8 & 1);
    const int byp = j8 >> 1;
    const int m0 = byp * 128, n0 = bxp * 64;
    const int wm = wave >> 1, wn = wave & 1;

    const short* Asrc = Ab + (size_t)m0 * K;
    const short* Bhsrc = Bh + (size_t)n0 * K;
    const short* Blsrc = Bl + (size_t)n0 * K;
    const int srow = lane >> 3;
    const int soff = (((lane & 7) ^ srow) * 8);

    floatx4 acc[4][2] = {};

    OSTAGE(0, 0);
    for (int t = 0; t < 16; ++t) {
        const int db = t & 1;
        if (t < 15) {
            OSTAGE(db ^ 1, (t + 1) * 64);
            asm volatile("s_waitcnt vmcnt(8)" ::: "memory");
        } else {
            asm volatile("s_waitcnt vmcnt(0)" ::: "memory");
        }
        __builtin_amdgcn_s_barrier();

#pragma unroll
        for (int s2 = 0; s2 < 2; ++s2) {
            short8 a_b[4], b_h[2], b_l[2];
#pragma unroll
            for (int mi = 0; mi < 4; ++mi) {
                int r = wm * 64 + mi * 16 + col;
                a_b[mi] = *(const short8*)&sA[db][r * 64 + SWZ8(r, s2 * 4 + quad)];
            }
#pragma unroll
            for (int ni = 0; ni < 2; ++ni) {
                int r = wn * 32 + ni * 16 + col;
                b_h[ni] = *(const short8*)&sBh[db][r * 64 + SWZ8(r, s2 * 4 + quad)];
                b_l[ni] = *(const short8*)&sBl[db][r * 64 + SWZ8(r, s2 * 4 + quad)];
            }
            __builtin_amdgcn_s_setprio(1);
#pragma unroll
            for (int mi = 0; mi < 4; ++mi)
#pragma unroll
                for (int ni = 0; ni < 2; ++ni) {
                    acc[mi][ni] = MFMA16(b_h[ni], a_b[mi], acc[mi][ni], 0, 0, 0);
                    acc[mi][ni] = MFMA16(b_l[ni], a_b[mi], acc[mi][ni], 0, 0, 0);
                }
            __builtin_amdgcn_s_setprio(0);
        }
        __builtin_amdgcn_s_barrier();
    }

    const int mb = m0 + wm * 64, nb = n0 + wn * 32;
#pragma unroll
    for (int mi = 0; mi < 4; ++mi) {
        int m = mb + mi * 16 + col;
#pragma unroll
        for (int ni = 0; ni < 2; ++ni) {
            int n = nb + ni * 16 + quad * 4;
            float4 bv = *(const float4*)&bias[n];
            float4 o = make_float4(acc[mi][ni][0] + bv.x, acc[mi][ni][1] + bv.y,
                                   acc[mi][ni][2] + bv.z, acc[mi][ni][3] + bv.w);
            *(float4*)&Of[(size_t)m * N + n] = o;
        }
    }
}

// ---------------------------------------------------------------------------
extern "C" void kernel_launch(void* const* d_in, const int* in_sizes, int n_in,
                              void* d_out, int out_size, void* d_ws, size_t ws_size,
                              hipStream_t stream) {
    const float* x  = (const float*)d_in[0];
    const float* Wq = (const float*)d_in[1];
    const float* Wk = (const float*)d_in[2];
    const float* Wv = (const float*)d_in[3];
    const float* Wo = (const float*)d_in[4];
    const float* bo = (const float*)d_in[5];
    float* out = (float*)d_out;

    const size_t NX = (size_t)BROWS * DMODEL;   // 4M
    const size_t NW = (size_t)DMODEL * DMODEL;  // 1M
    short* p = (short*)d_ws;
    short *xb = p;
    short *wqb = xb + NX;
    short *wkb = wqb + NW;
    short *wvb = wkb + NW;
    short *woh = wvb + NW; short *wol = woh + NW;
    short *qb = wol + NW;
    short *kb = qb + NX;
    short *vb = kb + NX;
    short *cb = vb + NX;

    PackArgs pa;
    pa.x = (const float4*)x; pa.xb = (ushort4*)xb;
    pa.w[0] = (const float4*)Wq; pa.wb[0] = (ushort4*)wqb;
    pa.w[1] = (const float4*)Wk; pa.wb[1] = (ushort4*)wkb;
    pa.w[2] = (const float4*)Wv; pa.wb[2] = (ushort4*)wvb;
    pa.wo = (const float4*)Wo; pa.woh = (ushort4*)woh; pa.wol = (ushort4*)wol;
    pack_all<<<dim3(1024, 5), dim3(256), 0, stream>>>(pa);

    gemm_qkv<<<dim3(3 * DMODEL / 128, BROWS / 128), dim3(256), 0, stream>>>(
        xb, wqb, wkb, wvb, qb, kb, vb);

    attn_bf16<<<dim3(TSEQ / 128, BH), dim3(512), 0, stream>>>(qb, kb, vb, cb);

    gemm_out<<<dim3(DMODEL / 64, BROWS / 128), dim3(256), 0, stream>>>(cb, woh, wol, bo, out);
}

// Round 12
// 174.172 us; speedup vs baseline: 1.1559x; 1.1559x over previous
//
#include <hip/hip_runtime.h>
#include <hip/hip_bf16.h>
#include <math.h>
#include <stdint.h>
#include <string.h>

#define TSEQ 2048
#define DMODEL 1024
#define NH 16
#define HD 64
#define BROWS 4096   // b*t
#define BH 32        // b*h

typedef __attribute__((ext_vector_type(8))) short short8;
typedef __attribute__((ext_vector_type(4))) float floatx4;

#define MFMA16 __builtin_amdgcn_mfma_f32_16x16x32_bf16
// 3-bit chunk-XOR swizzle on 64-short (128 B) rows
#define SWZ8(r, q) ((((q) ^ ((r) & 7)) * 8))

#define QSCALE 0.18033688011112042f   // 0.125 * log2(e); p = exp2(s) = exp(s/log2e)

__device__ __forceinline__ unsigned short bf16_rne(float f) {
    uint32_t u = __float_as_uint(f);
    u += 0x7FFFu + ((u >> 16) & 1u);
    return (unsigned short)(u >> 16);
}

__device__ __forceinline__ uint32_t pack_bf16x2(float a, float b) {
    __hip_bfloat162 h = __float22bfloat162_rn(float2{a, b});
    uint32_t r;
    memcpy(&r, &h, 4);
    return r;
}

__device__ __forceinline__ void split_bf16(float f, short& hi, short& lo) {
    uint32_t u = __float_as_uint(f);
    hi = (short)(u >> 16);
    float hif = __uint_as_float(u & 0xFFFF0000u);
    lo = (short)bf16_rne(f - hif);
}

__device__ __forceinline__ void async16(const void* g, void* l) {
    __builtin_amdgcn_global_load_lds(
        (__attribute__((address_space(1))) const uint32_t*)g,
        (__attribute__((address_space(3))) uint32_t*)l, 16, 0, 0);
}

// ---------------------------------------------------------------------------
// Fused pack (unchanged)
// ---------------------------------------------------------------------------
struct PackArgs {
    const float4* x;
    ushort4* xb;
    const float4* w[3];   // Wq, Wk, Wv
    ushort4* wb[3];
    const float4* wo;
    ushort4* woh;
    ushort4* wol;
};
__global__ __launch_bounds__(256) void pack_all(PackArgs a) {
    const int y = blockIdx.y;
    const int base = blockIdx.x * 256 + threadIdx.x;
    if (y == 0) {
#pragma unroll
        for (int it = 0; it < 4; ++it) {
            int i = base + it * 262144;
            float4 f = a.x[i];
            a.xb[i] = make_ushort4(bf16_rne(f.x), bf16_rne(f.y),
                                   bf16_rne(f.z), bf16_rne(f.w));
        }
    } else if (y <= 3) {
        int w = y - 1;
        float4 f = a.w[w][base];
        a.wb[w][base] = make_ushort4(bf16_rne(f.x), bf16_rne(f.y),
                                     bf16_rne(f.z), bf16_rne(f.w));
    } else {
        float4 f = a.wo[base];
        short h0, l0, h1, l1, h2, l2, h3, l3;
        split_bf16(f.x, h0, l0); split_bf16(f.y, h1, l1);
        split_bf16(f.z, h2, l2); split_bf16(f.w, h3, l3);
        a.woh[base] = make_ushort4(h0, h1, h2, h3);
        a.wol[base] = make_ushort4(l0, l1, l2, l3);
    }
}

// ---------------------------------------------------------------------------
// Fused QKV GEMM (R12): R7-form + single-barrier K-loop.
// Per K-step: vmcnt(0); barrier; stage(t+1 -> other buf); compute(buf t).
// Barrier collectively proves all waves finished reading the other buf
// (their previous compute) -> post-barrier stage into it is race-free.
// ---------------------------------------------------------------------------
#define QSTAGE(DB, K0)                                                          \
    {                                                                           \
        _Pragma("unroll")                                                       \
        for (int j = 0; j < 8; ++j) {                                           \
            int idx = wave * 8 + j;                                             \
            int sub = idx & 15;                                                 \
            const short* s = (idx < 16) ? Asrc : Bsrc;                          \
            short* d = (idx < 16) ? sA[DB] : sB[DB];                            \
            async16(s + (size_t)(sub * 8 + srow) * K + (K0) + soff, d + sub * 512); \
        }                                                                       \
    }

__global__ __launch_bounds__(256) void gemm_qkv(
    const short* __restrict__ Xb,
    const short* __restrict__ Bq, const short* __restrict__ Bk,
    const short* __restrict__ Bv,
    short* __restrict__ Qo, short* __restrict__ Ko, short* __restrict__ Vo) {
    __shared__ short sA[2][128 * 64];
    __shared__ short sB[2][128 * 64];
    const int K = DMODEL;

    const int tid = threadIdx.x;
    const int lane = tid & 63, wave = tid >> 6;
    const int quad = lane >> 4, col = lane & 15;

    // XCD swizzle: lin = by*24+bx; xcd owns bx' = 3*xcd + (j%3), all by'
    const int lin = blockIdx.y * 24 + blockIdx.x;
    const int xcd = lin & 7, j8 = lin >> 3;          // j8 in [0,96)
    const int bxp = 3 * xcd + (j8 % 3);
    const int byp = j8 / 3;
    const int m0 = byp * 128, n0 = bxp * 128;
    const int which = n0 >> 10;
    const int nn0 = n0 & 1023;
    const int wm = wave >> 1, wn = wave & 1;

    const short* B = (which == 0) ? Bq : (which == 1) ? Bk : Bv;
    const short* Asrc = Xb + (size_t)m0 * K;
    const short* Bsrc = B + (size_t)nn0 * K;

    const int srow = lane >> 3;
    const int soff = (((lane & 7) ^ srow) * 8);

    floatx4 acc[4][4] = {};

    QSTAGE(0, 0);
    for (int t = 0; t < 16; ++t) {
        const int db = t & 1;
        asm volatile("s_waitcnt vmcnt(0)" ::: "memory");
        __builtin_amdgcn_s_barrier();
        if (t < 15) {
            QSTAGE(db ^ 1, (t + 1) * 64);
        }

#pragma unroll
        for (int s2 = 0; s2 < 2; ++s2) {
            short8 a_b[4], b_b[4];
#pragma unroll
            for (int mi = 0; mi < 4; ++mi) {
                int r = wm * 64 + mi * 16 + col;
                a_b[mi] = *(const short8*)&sA[db][r * 64 + SWZ8(r, s2 * 4 + quad)];
            }
#pragma unroll
            for (int ni = 0; ni < 4; ++ni) {
                int r = wn * 64 + ni * 16 + col;
                b_b[ni] = *(const short8*)&sB[db][r * 64 + SWZ8(r, s2 * 4 + quad)];
            }
            __builtin_amdgcn_s_setprio(1);
            if (which == 2) {
#pragma unroll
                for (int mi = 0; mi < 4; ++mi)
#pragma unroll
                    for (int ni = 0; ni < 4; ++ni)
                        acc[mi][ni] = MFMA16(a_b[mi], b_b[ni], acc[mi][ni], 0, 0, 0);
            } else {
#pragma unroll
                for (int mi = 0; mi < 4; ++mi)
#pragma unroll
                    for (int ni = 0; ni < 4; ++ni)
                        acc[mi][ni] = MFMA16(b_b[ni], a_b[mi], acc[mi][ni], 0, 0, 0);
            }
            __builtin_amdgcn_s_setprio(0);
        }
    }

    const int mb = m0 + wm * 64;
    const int nlb = nn0 + wn * 64;
    if (which == 2) {
        // V^T [bh][hd][t], kappa-permuted window position + chunk-XOR swizzle
#pragma unroll
        for (int ni = 0; ni < 4; ++ni) {
            int n = nlb + ni * 16 + col;
            int h = n >> 6, hd = n & 63;
#pragma unroll
            for (int mi = 0; mi < 4; ++mi) {
                int m4 = mb + mi * 16 + quad * 4;
                int b = m4 >> 11, t0 = m4 & 2047;
                // kappa^-1: key bits [t5][t4][t3t2][t1t0] -> s = [t5][t3t2][t4][t1t0]
                int sw = (t0 & 32) | ((t0 & 12) << 1) | ((t0 & 16) >> 2);
                int tsw = (t0 & ~63) | ((((sw >> 3) ^ (hd & 7)) << 3) | (sw & 7));
                size_t row = ((size_t)(b * NH + h) * HD + hd) * TSEQ;
                *(ushort4*)&Vo[row + tsw] =
                    make_ushort4(bf16_rne(acc[mi][ni][0]), bf16_rne(acc[mi][ni][1]),
                                 bf16_rne(acc[mi][ni][2]), bf16_rne(acc[mi][ni][3]));
            }
        }
    } else {
        short* O = (which == 0) ? Qo : Ko;
        const float sc = (which == 0) ? QSCALE : 1.0f;
#pragma unroll
        for (int mi = 0; mi < 4; ++mi) {
            int m = mb + mi * 16 + col;
            int b = m >> 11, t = m & 2047;
#pragma unroll
            for (int ni = 0; ni < 4; ++ni) {
                int n = nlb + ni * 16 + quad * 4;
                int h = n >> 6, hd = n & 63;
                int hds = (which == 1) ? ((((hd >> 3) ^ (t & 7)) << 3) | (hd & 7)) : hd;
                size_t idx = ((size_t)(b * NH + h) * TSEQ + t) * HD + hds;
                *(ushort4*)&O[idx] =
                    make_ushort4(bf16_rne(acc[mi][ni][0] * sc), bf16_rne(acc[mi][ni][1] * sc),
                                 bf16_rne(acc[mi][ni][2] * sc), bf16_rne(acc[mi][ni][3] * sc));
            }
        }
    }
}

// ---------------------------------------------------------------------------
// Flash attention (R12): R8 form (best: 49.3 us) + single-barrier loop.
// Per 64-key tile: vmcnt(0); barrier; stage(next tile -> other buf);
// compute(cur buf). One barrier per tile instead of two.
// T15 2-deep pipeline retained. No XCD swizzle (R7: not BW-bound).
// ---------------------------------------------------------------------------
#define QK_U(DB, U, S)                                                          \
    {                                                                           \
        __builtin_amdgcn_s_setprio(1);                                          \
        _Pragma("unroll")                                                       \
        for (int k4 = 0; k4 < 4; ++k4) {                                        \
            short8 kf0 = *(const short8*)(kb0 + (DB) * 8192 + (U) * 4096 + k4 * 1024); \
            short8 kf1 = *(const short8*)(kb1 + (DB) * 8192 + (U) * 4096 + k4 * 1024); \
            S[k4] = MFMA16(kf0, qf[0], S[k4], 0, 0, 0);                         \
            S[k4] = MFMA16(kf1, qf[1], S[k4], 0, 0, 0);                         \
        }                                                                       \
        __builtin_amdgcn_s_setprio(0);                                          \
    }

// pf word c from s: 8 exp2 + 4 cvt_pk
#define EXPPACK_C(S, C, PFW)                                                    \
    {                                                                           \
        float p0 = __builtin_amdgcn_exp2f(S[2 * (C)][0]);                       \
        float p1 = __builtin_amdgcn_exp2f(S[2 * (C)][1]);                       \
        float p2 = __builtin_amdgcn_exp2f(S[2 * (C)][2]);                       \
        float p3 = __builtin_amdgcn_exp2f(S[2 * (C)][3]);                       \
        float p4 = __builtin_amdgcn_exp2f(S[2 * (C) + 1][0]);                   \
        float p5 = __builtin_amdgcn_exp2f(S[2 * (C) + 1][1]);                   \
        float p6 = __builtin_amdgcn_exp2f(S[2 * (C) + 1][2]);                   \
        float p7 = __builtin_amdgcn_exp2f(S[2 * (C) + 1][3]);                   \
        PFW.w[0] = pack_bf16x2(p0, p1);                                         \
        PFW.w[1] = pack_bf16x2(p2, p3);                                         \
        PFW.w[2] = pack_bf16x2(p4, p5);                                         \
        PFW.w[3] = pack_bf16x2(p6, p7);                                         \
    }

#define PV_C(DB, U, C, PFW)                                                     \
    {                                                                           \
        const short* vbc = (C) ? vb1 : vb0;                                     \
        __builtin_amdgcn_s_setprio(1);                                          \
        lacc = MFMA16(ones.v, PFW.v, lacc, 0, 0, 0);                            \
        _Pragma("unroll")                                                       \
        for (int ni = 0; ni < 4; ++ni) {                                        \
            short8 vf = *(const short8*)(vbc + (DB) * 8192 + (U) * 4096 + ni * 1024); \
            O[ni] = MFMA16(vf, PFW.v, O[ni], 0, 0, 0);                          \
        }                                                                       \
        __builtin_amdgcn_s_setprio(0);                                          \
    }

typedef union { short8 v; uint32_t w[4]; } pfu;

#define ATTN_COMPUTE(DB)                                                        \
    {                                                                           \
        floatx4 sa[4] = {};                                                     \
        QK_U(DB, 0, sa);                                                        \
        pfu pfA0, pfA1;                                                         \
        EXPPACK_C(sa, 0, pfA0);                                                 \
        EXPPACK_C(sa, 1, pfA1);                                                 \
        floatx4 sb[4] = {};                                                     \
        QK_U(DB, 1, sb);                                                        \
        /* PV(u0) MFMA interleaved with exp/pack(u1) VALU (independent) */      \
        pfu pfB0, pfB1;                                                         \
        PV_C(DB, 0, 0, pfA0);                                                   \
        EXPPACK_C(sb, 0, pfB0);                                                 \
        PV_C(DB, 0, 1, pfA1);                                                   \
        EXPPACK_C(sb, 1, pfB1);                                                 \
        PV_C(DB, 1, 0, pfB0);                                                   \
        PV_C(DB, 1, 1, pfB1);                                                   \
    }

#define ASTAGE(LB)                                                              \
    {                                                                           \
        async16(g0, (LB) + 0 * 512);                                            \
        async16(g1, (LB) + 1 * 512);                                            \
        async16(g2, (LB) + 2 * 512);                                            \
        async16(g3, (LB) + 3 * 512);                                            \
        g0 += ktstep; g1 += ktstep; g2 += ktstep; g3 += ktstep;                 \
    }

__global__ __launch_bounds__(512, 4) void attn_bf16(
    const short* __restrict__ Qb, const short* __restrict__ Kb,
    const short* __restrict__ Vb, short* __restrict__ Cb) {
    __shared__ short sK[2][2][64 * 64];   // [dbuf][tile]
    __shared__ short sV[2][2][64 * 64];

    const int tid = threadIdx.x;
    const int lane = tid & 63, wave = tid >> 6;
    const int quad = lane >> 4, col = lane & 15;
    const int qt = blockIdx.x, bh = blockIdx.y;
    const size_t bhoff = (size_t)bh * TSEQ * HD;

    // Q as B-operand frags: B[n=q=col][k=quad*8+j]
    const size_t qrow = (size_t)(qt * 128 + wave * 16 + col) * HD;
    short8 qf[2];
#pragma unroll
    for (int c = 0; c < 2; ++c)
        qf[c] = *(const short8*)&Qb[bhoff + qrow + c * 32 + quad * 8];

    const int srow = lane >> 3;
    const int schunk = (lane & 7) * 8;   // K/V globally pre-swizzled

    // staging geometry: wave w stages 4 slots n = w*4 + j
    const int isV = wave >> 2;
    const int tl = (wave >> 1) & 1;
    const int sb = (wave & 1) * 4;

    const short *g0, *g1, *g2, *g3;
    size_t ktstep;
    if (!isV) {
        g0 = Kb + bhoff + (size_t)(tl * 64 + (sb + 0) * 8 + srow) * HD + schunk;
        g1 = Kb + bhoff + (size_t)(tl * 64 + (sb + 1) * 8 + srow) * HD + schunk;
        g2 = Kb + bhoff + (size_t)(tl * 64 + (sb + 2) * 8 + srow) * HD + schunk;
        g3 = Kb + bhoff + (size_t)(tl * 64 + (sb + 3) * 8 + srow) * HD + schunk;
        ktstep = (size_t)128 * HD;
    } else {
        g0 = Vb + bhoff + (size_t)((sb + 0) * 8 + srow) * TSEQ + tl * 64 + schunk;
        g1 = Vb + bhoff + (size_t)((sb + 1) * 8 + srow) * TSEQ + tl * 64 + schunk;
        g2 = Vb + bhoff + (size_t)((sb + 2) * 8 + srow) * TSEQ + tl * 64 + schunk;
        g3 = Vb + bhoff + (size_t)((sb + 3) * 8 + srow) * TSEQ + tl * 64 + schunk;
        ktstep = 128;
    }
    short* lb0_ = isV ? &sV[0][tl][sb * 512] : &sK[0][tl][sb * 512];
    short* lb1_ = isV ? &sV[1][tl][sb * 512] : &sK[1][tl][sb * 512];

    // LDS fragment-read bases: all ds_reads are base + compile-time imm.
    const int ch0 = ((quad ^ (col & 7)) << 3);
    const int ch1 = (((4 + quad) ^ (col & 7)) << 3);
    const short* kb0 = &sK[0][0][col * 64 + ch0];
    const short* kb1 = &sK[0][0][col * 64 + ch1];
    const short* vb0 = &sV[0][0][col * 64 + ch0];
    const short* vb1 = &sV[0][0][col * 64 + ch1];

    // bf16 1.0 x8 for the l-accumulating MFMA
    union { short8 v; short s[8]; } ones;
#pragma unroll
    for (int j = 0; j < 8; ++j) ones.s[j] = (short)0x3F80;

    floatx4 lacc = {};      // every element = running l for q = col
    floatx4 O[4] = {};      // O^T: hd = ni*16 + quad*4 + r, q = col

    ASTAGE(lb0_);           // tile 0 -> db0

    for (int kt2 = 0; kt2 < 8; ++kt2) {
        // tile 2*kt2 (db0): barrier proves db1 reads (tile 2*kt2-1) done
        asm volatile("s_waitcnt vmcnt(0)" ::: "memory");
        __builtin_amdgcn_s_barrier();
        ASTAGE(lb1_);                    // stage tile 2*kt2+1 -> db1
        ATTN_COMPUTE(0);

        // tile 2*kt2+1 (db1): barrier proves db0 reads done
        asm volatile("s_waitcnt vmcnt(0)" ::: "memory");
        __builtin_amdgcn_s_barrier();
        if (kt2 < 7) {
            ASTAGE(lb0_);                // stage tile 2*kt2+2 -> db0
        }
        ATTN_COMPUTE(1);
    }

    // l is fully summed over all keys by the ones-MFMA (B-layout spans k=0..31)
    const float inv = 1.0f / lacc[0];

    const int b = bh >> 4, h = bh & 15;
    const int trow = qt * 128 + wave * 16 + col;
    const size_t obase = (size_t)(b * TSEQ + trow) * DMODEL + h * 64;
#pragma unroll
    for (int ni = 0; ni < 4; ++ni) {
        uint2 pk;
        pk.x = pack_bf16x2(O[ni][0] * inv, O[ni][1] * inv);
        pk.y = pack_bf16x2(O[ni][2] * inv, O[ni][3] * inv);
        *(uint2*)&Cb[obase + ni * 16 + quad * 4] = pk;
    }
}

// ---------------------------------------------------------------------------
// Out-proj 2-term (R12): R7 form + single-barrier K-loop + XCD swizzle.
// ---------------------------------------------------------------------------
#define OSTAGE(DB, K0)                                                          \
    {                                                                           \
        _Pragma("unroll")                                                       \
        for (int j = 0; j < 8; ++j) {                                           \
            int idx = wave * 8 + j;                                             \
            int buf = (idx < 16) ? 0 : (idx < 24) ? 1 : 2;                      \
            int sub = (buf == 0) ? idx : (buf == 1) ? idx - 16 : idx - 24;      \
            const short* s = (buf == 0) ? Asrc : (buf == 1) ? Bhsrc : Blsrc;    \
            short* d = (buf == 0) ? sA[DB] : (buf == 1) ? sBh[DB] : sBl[DB];    \
            async16(s + (size_t)(sub * 8 + srow) * K + (K0) + soff, d + sub * 512); \
        }                                                                       \
    }

__global__ __launch_bounds__(256) void gemm_out(
    const short* __restrict__ Ab,
    const short* __restrict__ Bh, const short* __restrict__ Bl,
    const float* __restrict__ bias, float* __restrict__ Of) {
    __shared__ short sA[2][128 * 64];
    __shared__ short sBh[2][64 * 64];
    __shared__ short sBl[2][64 * 64];
    const int K = DMODEL, N = DMODEL;

    const int tid = threadIdx.x;
    const int lane = tid & 63, wave = tid >> 6;
    const int quad = lane >> 4, col = lane & 15;

    // XCD swizzle: lin = by*16+bx; xcd owns bx' = 2*xcd + (j&1), all by'
    const int lin = blockIdx.y * 16 + blockIdx.x;
    const int xcd = lin & 7, j8 = lin >> 3;          // j8 in [0,64)
    const int bxp = 2 * xcd + (j8 & 1);
    const int byp = j8 >> 1;
    const int m0 = byp * 128, n0 = bxp * 64;
    const int wm = wave >> 1, wn = wave & 1;

    const short* Asrc = Ab + (size_t)m0 * K;
    const short* Bhsrc = Bh + (size_t)n0 * K;
    const short* Blsrc = Bl + (size_t)n0 * K;
    const int srow = lane >> 3;
    const int soff = (((lane & 7) ^ srow) * 8);

    floatx4 acc[4][2] = {};

    OSTAGE(0, 0);
    for (int t = 0; t < 16; ++t) {
        const int db = t & 1;
        asm volatile("s_waitcnt vmcnt(0)" ::: "memory");
        __builtin_amdgcn_s_barrier();
        if (t < 15) {
            OSTAGE(db ^ 1, (t + 1) * 64);
        }

#pragma unroll
        for (int s2 = 0; s2 < 2; ++s2) {
            short8 a_b[4], b_h[2], b_l[2];
#pragma unroll
            for (int mi = 0; mi < 4; ++mi) {
                int r = wm * 64 + mi * 16 + col;
                a_b[mi] = *(const short8*)&sA[db][r * 64 + SWZ8(r, s2 * 4 + quad)];
            }
#pragma unroll
            for (int ni = 0; ni < 2; ++ni) {
                int r = wn * 32 + ni * 16 + col;
                b_h[ni] = *(const short8*)&sBh[db][r * 64 + SWZ8(r, s2 * 4 + quad)];
                b_l[ni] = *(const short8*)&sBl[db][r * 64 + SWZ8(r, s2 * 4 + quad)];
            }
            __builtin_amdgcn_s_setprio(1);
#pragma unroll
            for (int mi = 0; mi < 4; ++mi)
#pragma unroll
                for (int ni = 0; ni < 2; ++ni) {
                    acc[mi][ni] = MFMA16(b_h[ni], a_b[mi], acc[mi][ni], 0, 0, 0);
                    acc[mi][ni] = MFMA16(b_l[ni], a_b[mi], acc[mi][ni], 0, 0, 0);
                }
            __builtin_amdgcn_s_setprio(0);
        }
    }

    const int mb = m0 + wm * 64, nb = n0 + wn * 32;
#pragma unroll
    for (int mi = 0; mi < 4; ++mi) {
        int m = mb + mi * 16 + col;
#pragma unroll
        for (int ni = 0; ni < 2; ++ni) {
            int n = nb + ni * 16 + quad * 4;
            float4 bv = *(const float4*)&bias[n];
            float4 o = make_float4(acc[mi][ni][0] + bv.x, acc[mi][ni][1] + bv.y,
                                   acc[mi][ni][2] + bv.z, acc[mi][ni][3] + bv.w);
            *(float4*)&Of[(size_t)m * N + n] = o;
        }
    }
}

// ---------------------------------------------------------------------------
extern "C" void kernel_launch(void* const* d_in, const int* in_sizes, int n_in,
                              void* d_out, int out_size, void* d_ws, size_t ws_size,
                              hipStream_t stream) {
    const float* x  = (const float*)d_in[0];
    const float* Wq = (const float*)d_in[1];
    const float* Wk = (const float*)d_in[2];
    const float* Wv = (const float*)d_in[3];
    const float* Wo = (const float*)d_in[4];
    const float* bo = (const float*)d_in[5];
    float* out = (float*)d_out;

    const size_t NX = (size_t)BROWS * DMODEL;   // 4M
    const size_t NW = (size_t)DMODEL * DMODEL;  // 1M
    short* p = (short*)d_ws;
    short *xb = p;
    short *wqb = xb + NX;
    short *wkb = wqb + NW;
    short *wvb = wkb + NW;
    short *woh = wvb + NW; short *wol = woh + NW;
    short *qb = wol + NW;
    short *kb = qb + NX;
    short *vb = kb + NX;
    short *cb = vb + NX;

    PackArgs pa;
    pa.x = (const float4*)x; pa.xb = (ushort4*)xb;
    pa.w[0] = (const float4*)Wq; pa.wb[0] = (ushort4*)wqb;
    pa.w[1] = (const float4*)Wk; pa.wb[1] = (ushort4*)wkb;
    pa.w[2] = (const float4*)Wv; pa.wb[2] = (ushort4*)wvb;
    pa.wo = (const float4*)Wo; pa.woh = (ushort4*)woh; pa.wol = (ushort4*)wol;
    pack_all<<<dim3(1024, 5), dim3(256), 0, stream>>>(pa);

    gemm_qkv<<<dim3(3 * DMODEL / 128, BROWS / 128), dim3(256), 0, stream>>>(
        xb, wqb, wkb, wvb, qb, kb, vb);

    attn_bf16<<<dim3(TSEQ / 128, BH), dim3(512), 0, stream>>>(qb, kb, vb, cb);

    gemm_out<<<dim3(DMODEL / 64, BROWS / 128), dim3(256), 0, stream>>>(cb, woh, wol, bo, out);
}